// Round 13
// baseline (259.638 us; speedup 1.0000x reference)
//
#include <hip/hip_runtime.h>
#include <hip/hip_bf16.h>

#define NA 8192
#define NB 2048
#define DIM 192
#define NH 4
#define DKH 48
#define TA 16
#define TB 32
#define PREC 200                       // floats per partial record (192 T + 4 l + 4 A)
#define SCALE 0.14433756729740643f     // 1/sqrt(48)
#define INVSCALE 6.928203230275509f    // sqrt(48)
#define NEGBIG 1e30f

typedef __bf16 bf16x8 __attribute__((ext_vector_type(8)));
typedef float f32x4 __attribute__((ext_vector_type(4)));

#define MFMA16(a, b, c) __builtin_amdgcn_mfma_f32_16x16x32_bf16(a, b, c, 0, 0, 0)

__device__ __forceinline__ float rsumg(float v) {
  v += __shfl_xor(v, 16, 64);
  v += __shfl_xor(v, 32, 64);
  return v;
}

// ---------------- fused prep: proj + maskdetect + woe + wstats ----------------
__global__ __launch_bounds__(256) void prep_kernel(
    const float* __restrict__ a_z, const float* __restrict__ bv_z,
    const float* __restrict__ Wq, const float* __restrict__ Wk, const float* __restrict__ Wv,
    const float* __restrict__ bq, const float* __restrict__ bk, const float* __restrict__ bvb,
    const float* __restrict__ Wo, const float* __restrict__ bo,
    const float* __restrict__ weight, const void* __restrict__ maskp,
    __bf16* __restrict__ Qo, __bf16* __restrict__ Ko, __bf16* __restrict__ Vo,
    float* __restrict__ WoeT, float* __restrict__ boe, int* __restrict__ mflag,
    float* __restrict__ MwG, float* __restrict__ LwG)
{
  const int blk = blockIdx.x;
  const int t = threadIdx.x;

  if (blk < 1536) {
    // ================= proj =================
    __shared__ float xs[8][DIM];
    const float* src; const float* W; const float* bias; int row0; int which;
    if (blk < 1024)      { src = a_z;  W = Wq; bias = bq;  row0 = blk * 8;          which = 0; }
    else if (blk < 1280) { src = bv_z; W = Wk; bias = bk;  row0 = (blk - 1024) * 8; which = 1; }
    else                 { src = bv_z; W = Wv; bias = bvb; row0 = (blk - 1280) * 8; which = 2; }
    for (int i = t; i < 8 * 48; i += 256) {
      int r = i / 48, c = i % 48;
      ((float4*)xs[r])[c] = ((const float4*)(src + (size_t)(row0 + r) * DIM))[c];
    }
    __syncthreads();
    if (t < 192) {
      float acc[8];
      float bb = bias[t];
      #pragma unroll
      for (int r = 0; r < 8; ++r) acc[r] = bb;
      const float4* wr = (const float4*)(W + (size_t)t * DIM);
      for (int c = 0; c < 48; ++c) {
        float4 w = wr[c];
        #pragma unroll
        for (int r = 0; r < 8; ++r) {
          float4 x = ((const float4*)xs[r])[c];
          acc[r] += w.x * x.x + w.y * x.y + w.z * x.z + w.w * x.w;
        }
      }
      int h = t / 48, dd = t % 48;
      if (which == 0) {
        #pragma unroll
        for (int r = 0; r < 8; ++r)
          Qo[((size_t)(row0 + r) * 4 + h) * 64 + dd] = (__bf16)acc[r];
      } else if (which == 1) {
        #pragma unroll
        for (int r = 0; r < 8; ++r)
          Ko[((size_t)h * NB + row0 + r) * 64 + dd] = (__bf16)acc[r];
      } else {
        bf16x8 pk;
        #pragma unroll
        for (int r = 0; r < 8; ++r) pk[r] = (__bf16)acc[r];
        *(bf16x8*)(Vo + (size_t)t * NB + row0) = pk;
      }
    }
    if (which == 0) {
      for (int i = t; i < 512; i += 256) {   // zero the K-pad [48,64)
        int r = i >> 6, hh = (i >> 4) & 3, kk = i & 15;
        Qo[((size_t)(row0 + r) * 4 + hh) * 64 + 48 + kk] = (__bf16)0.f;
      }
    } else if (which == 1) {
      for (int i = t; i < 512; i += 256) {
        int r = i >> 6, hh = (i >> 4) & 3, kk = i & 15;
        Ko[((size_t)hh * NB + row0 + r) * 64 + 48 + kk] = (__bf16)0.f;
      }
    }
  } else if (blk == 1536) {
    // ================= mask detect =================
    __shared__ int fl;
    if (t == 0) fl = 0;
    __syncthreads();
    const unsigned int* mw = (const unsigned int*)maskp;
    for (int i = t; i < 1024; i += 256) {
      unsigned int v = mw[i];
      if (v == 0x3F800000u) atomicMax(&fl, 2);
      else if (v > 1u) atomicMax(&fl, 1);
    }
    __syncthreads();
    if (t == 0) *mflag = fl;
  } else if (blk < 1573) {
    // ================= Wo_eff^T =================
    int i = (blk - 1537) * 256 + t;
    if (i < DIM * DKH) {
      int k = i / DKH, d = i % DKH;
      float s = 0.25f * (Wo[(size_t)d * DIM + k] + Wo[(size_t)(d + 48) * DIM + k] +
                         Wo[(size_t)(d + 96) * DIM + k] + Wo[(size_t)(d + 144) * DIM + k]);
      WoeT[k * DKH + d] = s;
    }
    if (i < DKH) boe[i] = 0.25f * (bo[i] + bo[i + 48] + bo[i + 96] + bo[i + 144]);
  } else {
    // ================= wstats (inline mask detect) =================
    __shared__ int fl;
    if (t == 0) fl = 0;
    __syncthreads();
    {
      const unsigned int* mw = (const unsigned int*)maskp;
      for (int i = t; i < 1024; i += 256) {
        unsigned int v = mw[i];
        if (v == 0x3F800000u) atomicMax(&fl, 2);
        else if (v > 1u) atomicMax(&fl, 1);
      }
    }
    __syncthreads();
    const int mmode = fl;
    const int lane = t & 63;
    const int a = (blk - 1573) * 4 + (t >> 6);
    const float* wr = weight + (size_t)a * NB;
    const unsigned char* m8 = (const unsigned char*)maskp + (size_t)a * NB;
    const float* mf = (const float*)maskp + (size_t)a * NB;
    const int* m32 = (const int*)maskp + (size_t)a * NB;

    float mloc = -NEGBIG, sloc = 0.f;
    for (int it = 0; it < 8; ++it) {
      int idx = it * 256 + lane * 4;
      float4 w4 = *(const float4*)(wr + idx);
      bool ok0, ok1, ok2, ok3;
      if (mmode == 1) {
        unsigned mm = *(const unsigned*)(m8 + idx);
        ok0 = mm & 0xffu; ok1 = (mm >> 8) & 0xffu; ok2 = (mm >> 16) & 0xffu; ok3 = mm >> 24;
      } else if (mmode == 2) {
        float4 mv = *(const float4*)(mf + idx);
        ok0 = mv.x != 0.f; ok1 = mv.y != 0.f; ok2 = mv.z != 0.f; ok3 = mv.w != 0.f;
      } else {
        int4 mv = *(const int4*)(m32 + idx);
        ok0 = mv.x; ok1 = mv.y; ok2 = mv.z; ok3 = mv.w;
      }
      float v0 = ok0 ? w4.x : -NEGBIG;
      float v1 = ok1 ? w4.y : -NEGBIG;
      float v2 = ok2 ? w4.z : -NEGBIG;
      float v3 = ok3 ? w4.w : -NEGBIG;
      float mt = fmaxf(fmaxf(v0, v1), fmaxf(v2, v3));
      float mn = fmaxf(mloc, mt);
      float sc = __expf(mloc - mn);
      float e0 = (v0 > -1e29f) ? __expf(v0 - mn) : 0.f;
      float e1 = (v1 > -1e29f) ? __expf(v1 - mn) : 0.f;
      float e2 = (v2 > -1e29f) ? __expf(v2 - mn) : 0.f;
      float e3 = (v3 > -1e29f) ? __expf(v3 - mn) : 0.f;
      sloc = sloc * sc + (e0 + e1) + (e2 + e3);
      mloc = mn;
    }
    float mfin = mloc;
    #pragma unroll
    for (int off = 1; off < 64; off <<= 1) mfin = fmaxf(mfin, __shfl_xor(mfin, off, 64));
    float sadj = sloc * __expf(mloc - mfin);
    #pragma unroll
    for (int off = 1; off < 64; off <<= 1) sadj += __shfl_xor(sadj, off, 64);
    if (lane == 0) { MwG[a] = mfin; LwG[a] = sadj; }
  }
}

// ---------------- VW = per-head V @ Woe_h ----------------
__global__ __launch_bounds__(256) void vw_kernel(
    const __bf16* __restrict__ Vt, const float* __restrict__ WoeT, __bf16* __restrict__ VWt)
{
  __shared__ float woe[DIM][DKH];
  const int t = threadIdx.x;
  for (int i = t; i < DIM * DKH / 4; i += 256)
    ((float4*)&woe[0][0])[i] = ((const float4*)WoeT)[i];
  __syncthreads();
  const int b = blockIdx.x * 16 + (t & 15);
  const int grp = t >> 4;
  const int h = grp >> 2;
  const int q = grp & 3;
  float acc[12];
  #pragma unroll
  for (int d = 0; d < 12; ++d) acc[d] = 0.f;
  for (int dp = 0; dp < DKH; ++dp) {
    float v = (float)Vt[(size_t)(h * DKH + dp) * NB + b];
    const float* wrow = &woe[h * DKH + dp][q * 12];
    #pragma unroll
    for (int d = 0; d < 12; ++d) acc[d] += v * wrow[d];
  }
  #pragma unroll
  for (int d = 0; d < 12; ++d)
    VWt[(size_t)(h * DKH + q * 12 + d) * NB + b] = (__bf16)acc[d];
}

// ---------------- fused MFMA attention: 2-tile ILP per wave iteration ----------------
// grid = ns * 512 blocks x 256 threads. Wave = head h. m == 0 fixed reference.
// Two independent tile chains (A = tile, B = tile+1) interleaved per loop body:
// one exposed-latency window covers both tiles; o-accumulators shared (no rescale).
template<int MMODE>
__global__ __launch_bounds__(256, 4) void attn_kernel(
    const __bf16* __restrict__ Qb, const __bf16* __restrict__ Kb, const __bf16* __restrict__ VWt,
    const float* __restrict__ weight, const void* __restrict__ maskp,
    const int* __restrict__ maskflag, const float* __restrict__ MwG,
    float* __restrict__ part, int tps)
{
  if (*maskflag != MMODE) return;   // wrong-mode instance: early out

  __shared__ __bf16 SsA[4][16][40];   // per-wave P staging, stream A
  __shared__ __bf16 SsB[4][16][40];   // stream B (same proven bank layout)

  const int t = threadIdx.x;
  const int lane = t & 63;
  const int h = t >> 6;
  const int c = lane & 15;          // actor col
  const int g = lane >> 4;
  const int g8 = g * 8;
  const int s = blockIdx.x >> 9;    // split
  const int a0 = (blockIdx.x & 511) * TA;
  const int tile0 = s * tps;
  const int tend = tile0 + tps;     // tps is even (16 or 32)

  const unsigned char* m8 = (const unsigned char*)maskp;
  const float* mfp = (const float*)maskp;
  const int* m32 = (const int*)maskp;

  // Q fragment (B-operand): col a = c, k contiguous
  const __bf16* qp = Qb + ((size_t)(a0 + c) * NH + h) * 64 + g8;
  const bf16x8 qf0 = *(const bf16x8*)qp;
  const bf16x8 qf1 = *(const bf16x8*)(qp + 32);

  const float MwC = MwG[a0 + c];
  float lp = 0.f, Ap = 0.f;
  f32x4 o0 = {0.f,0.f,0.f,0.f}, o1 = {0.f,0.f,0.f,0.f}, o2 = {0.f,0.f,0.f,0.f};

  const size_t wrow = (size_t)(a0 + c) * NB + g * 4;

#define ISSUE_W(T, W0, W1, MX, MY, MA, MB)                                        \
  do {                                                                            \
    size_t gi = wrow + (size_t)(T) * TB;                                          \
    W0 = *(const float4*)(weight + gi);                                           \
    W1 = *(const float4*)(weight + gi + 16);                                      \
    if constexpr (MMODE == 1)      { MX = *(const int*)(m8 + gi);                 \
                                     MY = *(const int*)(m8 + gi + 16); }          \
    else if constexpr (MMODE == 2) { MA = *(const int4*)(mfp + gi);               \
                                     MB = *(const int4*)(mfp + gi + 16); }        \
    else                           { MA = *(const int4*)(m32 + gi);               \
                                     MB = *(const int4*)(m32 + gi + 16); }        \
  } while (0)

#define CONVERT_W(WV, W0, W1, MX, MY, MA, MB)                                     \
  do {                                                                            \
    if constexpr (MMODE == 1) {                                                   \
      unsigned ua = (unsigned)MX, ub = (unsigned)MY;                              \
      WV[0] = (ua & 0xffu)         ? W0.x : -NEGBIG;                              \
      WV[1] = ((ua >> 8) & 0xffu)  ? W0.y : -NEGBIG;                              \
      WV[2] = ((ua >> 16) & 0xffu) ? W0.z : -NEGBIG;                              \
      WV[3] = (ua >> 24)           ? W0.w : -NEGBIG;                              \
      WV[4] = (ub & 0xffu)         ? W1.x : -NEGBIG;                              \
      WV[5] = ((ub >> 8) & 0xffu)  ? W1.y : -NEGBIG;                              \
      WV[6] = ((ub >> 16) & 0xffu) ? W1.z : -NEGBIG;                              \
      WV[7] = (ub >> 24)           ? W1.w : -NEGBIG;                              \
    } else if constexpr (MMODE == 2) {                                            \
      WV[0] = (((unsigned)MA.x << 1) != 0u) ? W0.x : -NEGBIG;                     \
      WV[1] = (((unsigned)MA.y << 1) != 0u) ? W0.y : -NEGBIG;                     \
      WV[2] = (((unsigned)MA.z << 1) != 0u) ? W0.z : -NEGBIG;                     \
      WV[3] = (((unsigned)MA.w << 1) != 0u) ? W0.w : -NEGBIG;                     \
      WV[4] = (((unsigned)MB.x << 1) != 0u) ? W1.x : -NEGBIG;                     \
      WV[5] = (((unsigned)MB.y << 1) != 0u) ? W1.y : -NEGBIG;                     \
      WV[6] = (((unsigned)MB.z << 1) != 0u) ? W1.z : -NEGBIG;                     \
      WV[7] = (((unsigned)MB.w << 1) != 0u) ? W1.w : -NEGBIG;                     \
    } else {                                                                      \
      WV[0] = MA.x ? W0.x : -NEGBIG;                                              \
      WV[1] = MA.y ? W0.y : -NEGBIG;                                              \
      WV[2] = MA.z ? W0.z : -NEGBIG;                                              \
      WV[3] = MA.w ? W0.w : -NEGBIG;                                              \
      WV[4] = MB.x ? W1.x : -NEGBIG;                                              \
      WV[5] = MB.y ? W1.y : -NEGBIG;                                              \
      WV[6] = MB.z ? W1.z : -NEGBIG;                                              \
      WV[7] = MB.w ? W1.w : -NEGBIG;                                              \
    }                                                                             \
  } while (0)

  // raw prefetch slots, stream A and B (named, rule #20)
  float4 wa0, wa1, wb0, wb1;
  int max_, may_, mbx_, mby_;
  int4 maA, maB, mbA, mbB;
  ISSUE_W(tile0,     wa0, wa1, max_, may_, maA, maB);
  ISSUE_W(tile0 + 1, wb0, wb1, mbx_, mby_, mbA, mbB);

  const __bf16* kbase = Kb + ((size_t)h * NB + c) * 64 + g8;
  const __bf16* vbase = VWt + ((size_t)(h * DKH + c)) * NB + g8;

  for (int u = tile0; u < tend; u += 2) {
    const int v = u + 1;

    // 1. K + VW loads for BOTH tiles (one latency window covers both)
    const __bf16* kpA = kbase + (size_t)u * TB * 64;
    bf16x8 kAA0 = *(const bf16x8*)kpA;
    bf16x8 kAA1 = *(const bf16x8*)(kpA + 32);
    bf16x8 kAB0 = *(const bf16x8*)(kpA + 16 * 64);
    bf16x8 kAB1 = *(const bf16x8*)(kpA + 16 * 64 + 32);
    const __bf16* kpB = kbase + (size_t)v * TB * 64;
    bf16x8 kBA0 = *(const bf16x8*)kpB;
    bf16x8 kBA1 = *(const bf16x8*)(kpB + 32);
    bf16x8 kBB0 = *(const bf16x8*)(kpB + 16 * 64);
    bf16x8 kBB1 = *(const bf16x8*)(kpB + 16 * 64 + 32);
    const __bf16* vpA = vbase + (size_t)u * TB;
    bf16x8 vfA0 = *(const bf16x8*)vpA;
    bf16x8 vfA1 = *(const bf16x8*)(vpA + 16 * NB);
    bf16x8 vfA2 = *(const bf16x8*)(vpA + 32 * NB);
    const __bf16* vpB = vbase + (size_t)v * TB;
    bf16x8 vfB0 = *(const bf16x8*)vpB;
    bf16x8 vfB1 = *(const bf16x8*)(vpB + 16 * NB);
    bf16x8 vfB2 = *(const bf16x8*)(vpB + 32 * NB);

    // 2. convert both weight tiles (waits front-of-queue raws from last iter)
    float wvA[8], wvB[8];
    CONVERT_W(wvA, wa0, wa1, max_, may_, maA, maB);
    CONVERT_W(wvB, wb0, wb1, mbx_, mby_, mbA, mbB);

    // 3. QK^T for both streams
    f32x4 accA0, accA1, accB0, accB1;
    #pragma unroll
    for (int j = 0; j < 4; ++j) {
      accA0[j] = wvA[j] * INVSCALE; accA1[j] = wvA[4 + j] * INVSCALE;
      accB0[j] = wvB[j] * INVSCALE; accB1[j] = wvB[4 + j] * INVSCALE;
    }
    accA0 = MFMA16(kAA0, qf0, accA0);
    accA0 = MFMA16(kAA1, qf1, accA0);
    accA1 = MFMA16(kAB0, qf0, accA1);
    accA1 = MFMA16(kAB1, qf1, accA1);
    accB0 = MFMA16(kBA0, qf0, accB0);
    accB0 = MFMA16(kBA1, qf1, accB0);
    accB1 = MFMA16(kBB0, qf0, accB1);
    accB1 = MFMA16(kBB1, qf1, accB1);

    // 4. reissue raw W slots for u+2 / v+2 (2 tiles of flight)
    __builtin_amdgcn_sched_barrier(0);
    {
      int un = (u + 2 < tend) ? u + 2 : u;
      int vn = (v + 2 < tend) ? v + 2 : v;
      ISSUE_W(un, wa0, wa1, max_, may_, maA, maB);
      ISSUE_W(vn, wb0, wb1, mbx_, mby_, mbA, mbB);
    }

    // 5. p = exp(sv) vs fixed 0 reference; influence inline; stage P
    #pragma unroll
    for (int j = 0; j < 4; ++j) {
      float s0 = accA0[j] * SCALE, s1 = accA1[j] * SCALE;
      float p0 = __expf(s0), p1 = __expf(s1);
      lp += p0 + p1;
      Ap += __expf(s0 + wvA[j] - MwC) + __expf(s1 + wvA[4 + j] - MwC);
      SsA[h][c][g * 4 + j]      = (__bf16)p0;
      SsA[h][c][16 + g * 4 + j] = (__bf16)p1;
    }
    #pragma unroll
    for (int j = 0; j < 4; ++j) {
      float s0 = accB0[j] * SCALE, s1 = accB1[j] * SCALE;
      float p0 = __expf(s0), p1 = __expf(s1);
      lp += p0 + p1;
      Ap += __expf(s0 + wvB[j] - MwC) + __expf(s1 + wvB[4 + j] - MwC);
      SsB[h][c][g * 4 + j]      = (__bf16)p0;
      SsB[h][c][16 + g * 4 + j] = (__bf16)p1;
    }
    __builtin_amdgcn_sched_barrier(0);
    bf16x8 pbA = *(const bf16x8*)&SsA[h][c][g8];
    bf16x8 pbB = *(const bf16x8*)&SsB[h][c][g8];

    // 6. PV for both streams into the SHARED accumulators (no rescale, m==0)
    o0 = MFMA16(vfA0, pbA, o0);
    o1 = MFMA16(vfA1, pbA, o1);
    o2 = MFMA16(vfA2, pbA, o2);
    o0 = MFMA16(vfB0, pbB, o0);
    o1 = MFMA16(vfB1, pbB, o1);
    o2 = MFMA16(vfB2, pbB, o2);
  }

  // ---- one wave-reduce at the end; write partial record ----
  float l = rsumg(lp);
  float A = rsumg(Ap);
  float* pr = part + ((size_t)s * NA + a0 + c) * PREC;
  #pragma unroll
  for (int j = 0; j < 4; ++j) {
    pr[h * 48 + g * 4 + j]      = o0[j];
    pr[h * 48 + 16 + g * 4 + j] = o1[j];
    pr[h * 48 + 32 + g * 4 + j] = o2[j];
  }
  if (g == 0) {
    pr[192 + h] = l;
    pr[196 + h] = A;
  }
#undef ISSUE_W
#undef CONVERT_W
}

// ---------------- merge splits: plain sums (shared m == 0 reference) ----------------
__global__ __launch_bounds__(256) void merge_kernel(
    const float* __restrict__ part, const float* __restrict__ LwG,
    const float* __restrict__ boe, float* __restrict__ out, int ns)
{
  __shared__ float fls[32][NH];      // 1/l per (a,h)
  __shared__ float infl[32][NH];
  const int t = threadIdx.x;
  const int a0 = blockIdx.x * 32;

  if (t < 128) {
    int a = t >> 2, hh = t & 3;
    const float* rec = part + (size_t)(a0 + a) * PREC;
    float lst = 0.f, As = 0.f;
    for (int s = 0; s < ns; ++s) {
      const float* r = rec + (size_t)s * NA * PREC;
      lst += r[192 + hh];
      As  += r[196 + hh];
    }
    float li = 1.f / lst;
    fls[a][hh] = li;
    infl[a][hh] = As * li;
  }
  __syncthreads();
  if (t < 32)
    out[(size_t)(a0 + t) * 49 + 48] =
        (infl[t][0] + infl[t][1] + infl[t][2] + infl[t][3]) / (4.f * LwG[a0 + t]);
  for (int i = t; i < 32 * DKH; i += 256) {
    int a = i / DKH, dd = i - a * DKH;
    float acc = boe[dd];
    const float* rec = part + (size_t)(a0 + a) * PREC;
    for (int s = 0; s < ns; ++s) {
      const float* r = rec + (size_t)s * NA * PREC;
      #pragma unroll
      for (int hh = 0; hh < NH; ++hh)
        acc += fls[a][hh] * r[hh * 48 + dd];
    }
    out[(size_t)(a0 + a) * 49 + dd] = acc;
  }
}

extern "C" void kernel_launch(void* const* d_in, const int* in_sizes, int n_in,
                              void* d_out, int out_size, void* d_ws, size_t ws_size,
                              hipStream_t stream) {
  const float* a_z    = (const float*)d_in[0];
  const float* bv_z   = (const float*)d_in[1];
  const float* weight = (const float*)d_in[2];
  const void*  maskp  = d_in[3];
  const float* Wq = (const float*)d_in[4];
  const float* Wk = (const float*)d_in[5];
  const float* Wv = (const float*)d_in[6];
  const float* Wo = (const float*)d_in[7];
  const float* bq = (const float*)d_in[8];
  const float* bk = (const float*)d_in[9];
  const float* bvb = (const float*)d_in[10];
  const float* bo = (const float*)d_in[11];

  __bf16* Qb  = (__bf16*)d_ws;                      // [NA][4][64]
  __bf16* Kb  = Qb + (size_t)NA * 256;              // [4][NB][64]
  __bf16* Vtg = Kb + (size_t)4 * NB * 64;           // [192][NB]
  __bf16* VWt = Vtg + (size_t)DIM * NB;             // [192][NB]
  float* WoeT = (float*)(VWt + (size_t)DIM * NB);   // [192][48]
  float* boe  = WoeT + DIM * DKH;
  int*  mflag = (int*)(boe + 64);
  float* MwG  = (float*)(mflag + 64);               // [NA]
  float* LwG  = MwG + NA;                           // [NA]
  float* part = LwG + NA;                           // [ns][NA][200]

  size_t base = (size_t)((char*)(part) - (char*)d_ws);
  int ns = (ws_size >= base + (size_t)4 * NA * PREC * 4) ? 4 : 2;
  int tps = (NB / TB) / ns;

  prep_kernel<<<3621, 256, 0, stream>>>(a_z, bv_z, Wq, Wk, Wv, bq, bk, bvb, Wo, bo,
                                        weight, maskp, Qb, Kb, Vtg, WoeT, boe, mflag,
                                        MwG, LwG);
  vw_kernel<<<NB / 16, 256, 0, stream>>>(Vtg, WoeT, VWt);
  attn_kernel<1><<<ns * 512, 256, 0, stream>>>(Qb, Kb, VWt, weight, maskp, mflag, MwG, part, tps);
  attn_kernel<0><<<ns * 512, 256, 0, stream>>>(Qb, Kb, VWt, weight, maskp, mflag, MwG, part, tps);
  attn_kernel<2><<<ns * 512, 256, 0, stream>>>(Qb, Kb, VWt, weight, maskp, mflag, MwG, part, tps);
  merge_kernel<<<NA / 32, 256, 0, stream>>>(part, LwG, boe, (float*)d_out, ns);
}

// Round 14
// 175.950 us; speedup vs baseline: 1.4756x; 1.4756x over previous
//
#include <hip/hip_runtime.h>
#include <hip/hip_bf16.h>

#define NA 8192
#define NB 2048
#define DIM 192
#define NH 4
#define DKH 48
#define TA 16
#define TB 32
#define PREC 200                       // floats per partial record (192 T + 4 l + 4 A)
#define SCALE 0.14433756729740643f     // 1/sqrt(48)
#define INVSCALE 6.928203230275509f    // sqrt(48)
#define NEGBIG 1e30f

typedef __bf16 bf16x8 __attribute__((ext_vector_type(8)));
typedef float f32x4 __attribute__((ext_vector_type(4)));

#define MFMA16(a, b, c) __builtin_amdgcn_mfma_f32_16x16x32_bf16(a, b, c, 0, 0, 0)

// async global->LDS, 16B per lane, dest = ldsbase + lane*16 (wave-uniform base)
#define GLDS(gp, lp)                                                      \
  __builtin_amdgcn_global_load_lds(                                       \
      (__attribute__((address_space(1))) void*)(const void*)(gp),         \
      (__attribute__((address_space(3))) void*)(void*)(lp), 16, 0, 0)

__device__ __forceinline__ float rsumg(float v) {
  v += __shfl_xor(v, 16, 64);
  v += __shfl_xor(v, 32, 64);
  return v;
}

// ---------------- fused prep: proj + maskdetect + woe + wstats ----------------
__global__ __launch_bounds__(256) void prep_kernel(
    const float* __restrict__ a_z, const float* __restrict__ bv_z,
    const float* __restrict__ Wq, const float* __restrict__ Wk, const float* __restrict__ Wv,
    const float* __restrict__ bq, const float* __restrict__ bk, const float* __restrict__ bvb,
    const float* __restrict__ Wo, const float* __restrict__ bo,
    const float* __restrict__ weight, const void* __restrict__ maskp,
    __bf16* __restrict__ Qo, __bf16* __restrict__ Ko, __bf16* __restrict__ Vo,
    float* __restrict__ WoeT, float* __restrict__ boe, int* __restrict__ mflag,
    float* __restrict__ MwG, float* __restrict__ LwG)
{
  const int blk = blockIdx.x;
  const int t = threadIdx.x;

  if (blk < 1536) {
    // ================= proj =================
    __shared__ float xs[8][DIM];
    const float* src; const float* W; const float* bias; int row0; int which;
    if (blk < 1024)      { src = a_z;  W = Wq; bias = bq;  row0 = blk * 8;          which = 0; }
    else if (blk < 1280) { src = bv_z; W = Wk; bias = bk;  row0 = (blk - 1024) * 8; which = 1; }
    else                 { src = bv_z; W = Wv; bias = bvb; row0 = (blk - 1280) * 8; which = 2; }
    for (int i = t; i < 8 * 48; i += 256) {
      int r = i / 48, c = i % 48;
      ((float4*)xs[r])[c] = ((const float4*)(src + (size_t)(row0 + r) * DIM))[c];
    }
    __syncthreads();
    if (t < 192) {
      float acc[8];
      float bb = bias[t];
      #pragma unroll
      for (int r = 0; r < 8; ++r) acc[r] = bb;
      const float4* wr = (const float4*)(W + (size_t)t * DIM);
      for (int c = 0; c < 48; ++c) {
        float4 w = wr[c];
        #pragma unroll
        for (int r = 0; r < 8; ++r) {
          float4 x = ((const float4*)xs[r])[c];
          acc[r] += w.x * x.x + w.y * x.y + w.z * x.z + w.w * x.w;
        }
      }
      int h = t / 48, dd = t % 48;
      if (which == 0) {
        #pragma unroll
        for (int r = 0; r < 8; ++r)
          Qo[((size_t)(row0 + r) * 4 + h) * 64 + dd] = (__bf16)acc[r];
      } else if (which == 1) {
        #pragma unroll
        for (int r = 0; r < 8; ++r)
          Ko[((size_t)h * NB + row0 + r) * 64 + dd] = (__bf16)acc[r];
      } else {
        bf16x8 pk;
        #pragma unroll
        for (int r = 0; r < 8; ++r) pk[r] = (__bf16)acc[r];
        *(bf16x8*)(Vo + (size_t)t * NB + row0) = pk;
      }
    }
    if (which == 0) {
      for (int i = t; i < 512; i += 256) {   // zero the K-pad [48,64)
        int r = i >> 6, hh = (i >> 4) & 3, kk = i & 15;
        Qo[((size_t)(row0 + r) * 4 + hh) * 64 + 48 + kk] = (__bf16)0.f;
      }
    } else if (which == 1) {
      for (int i = t; i < 512; i += 256) {
        int r = i >> 6, hh = (i >> 4) & 3, kk = i & 15;
        Ko[((size_t)hh * NB + row0 + r) * 64 + 48 + kk] = (__bf16)0.f;
      }
    }
  } else if (blk == 1536) {
    // ================= mask detect =================
    __shared__ int fl;
    if (t == 0) fl = 0;
    __syncthreads();
    const unsigned int* mw = (const unsigned int*)maskp;
    for (int i = t; i < 1024; i += 256) {
      unsigned int v = mw[i];
      if (v == 0x3F800000u) atomicMax(&fl, 2);
      else if (v > 1u) atomicMax(&fl, 1);
    }
    __syncthreads();
    if (t == 0) *mflag = fl;
  } else if (blk < 1573) {
    // ================= Wo_eff^T =================
    int i = (blk - 1537) * 256 + t;
    if (i < DIM * DKH) {
      int k = i / DKH, d = i % DKH;
      float s = 0.25f * (Wo[(size_t)d * DIM + k] + Wo[(size_t)(d + 48) * DIM + k] +
                         Wo[(size_t)(d + 96) * DIM + k] + Wo[(size_t)(d + 144) * DIM + k]);
      WoeT[k * DKH + d] = s;
    }
    if (i < DKH) boe[i] = 0.25f * (bo[i] + bo[i + 48] + bo[i + 96] + bo[i + 144]);
  } else {
    // ================= wstats (inline mask detect) =================
    __shared__ int fl;
    if (t == 0) fl = 0;
    __syncthreads();
    {
      const unsigned int* mw = (const unsigned int*)maskp;
      for (int i = t; i < 1024; i += 256) {
        unsigned int v = mw[i];
        if (v == 0x3F800000u) atomicMax(&fl, 2);
        else if (v > 1u) atomicMax(&fl, 1);
      }
    }
    __syncthreads();
    const int mmode = fl;
    const int lane = t & 63;
    const int a = (blk - 1573) * 4 + (t >> 6);
    const float* wr = weight + (size_t)a * NB;
    const unsigned char* m8 = (const unsigned char*)maskp + (size_t)a * NB;
    const float* mf = (const float*)maskp + (size_t)a * NB;
    const int* m32 = (const int*)maskp + (size_t)a * NB;

    float mloc = -NEGBIG, sloc = 0.f;
    for (int it = 0; it < 8; ++it) {
      int idx = it * 256 + lane * 4;
      float4 w4 = *(const float4*)(wr + idx);
      bool ok0, ok1, ok2, ok3;
      if (mmode == 1) {
        unsigned mm = *(const unsigned*)(m8 + idx);
        ok0 = mm & 0xffu; ok1 = (mm >> 8) & 0xffu; ok2 = (mm >> 16) & 0xffu; ok3 = mm >> 24;
      } else if (mmode == 2) {
        float4 mv = *(const float4*)(mf + idx);
        ok0 = mv.x != 0.f; ok1 = mv.y != 0.f; ok2 = mv.z != 0.f; ok3 = mv.w != 0.f;
      } else {
        int4 mv = *(const int4*)(m32 + idx);
        ok0 = mv.x; ok1 = mv.y; ok2 = mv.z; ok3 = mv.w;
      }
      float v0 = ok0 ? w4.x : -NEGBIG;
      float v1 = ok1 ? w4.y : -NEGBIG;
      float v2 = ok2 ? w4.z : -NEGBIG;
      float v3 = ok3 ? w4.w : -NEGBIG;
      float mt = fmaxf(fmaxf(v0, v1), fmaxf(v2, v3));
      float mn = fmaxf(mloc, mt);
      float sc = __expf(mloc - mn);
      float e0 = (v0 > -1e29f) ? __expf(v0 - mn) : 0.f;
      float e1 = (v1 > -1e29f) ? __expf(v1 - mn) : 0.f;
      float e2 = (v2 > -1e29f) ? __expf(v2 - mn) : 0.f;
      float e3 = (v3 > -1e29f) ? __expf(v3 - mn) : 0.f;
      sloc = sloc * sc + (e0 + e1) + (e2 + e3);
      mloc = mn;
    }
    float mfin = mloc;
    #pragma unroll
    for (int off = 1; off < 64; off <<= 1) mfin = fmaxf(mfin, __shfl_xor(mfin, off, 64));
    float sadj = sloc * __expf(mloc - mfin);
    #pragma unroll
    for (int off = 1; off < 64; off <<= 1) sadj += __shfl_xor(sadj, off, 64);
    if (lane == 0) { MwG[a] = mfin; LwG[a] = sadj; }
  }
}

// ---------------- VW = per-head V @ Woe_h ----------------
__global__ __launch_bounds__(256) void vw_kernel(
    const __bf16* __restrict__ Vt, const float* __restrict__ WoeT, __bf16* __restrict__ VWt)
{
  __shared__ float woe[DIM][DKH];
  const int t = threadIdx.x;
  for (int i = t; i < DIM * DKH / 4; i += 256)
    ((float4*)&woe[0][0])[i] = ((const float4*)WoeT)[i];
  __syncthreads();
  const int b = blockIdx.x * 16 + (t & 15);
  const int grp = t >> 4;
  const int h = grp >> 2;
  const int q = grp & 3;
  float acc[12];
  #pragma unroll
  for (int d = 0; d < 12; ++d) acc[d] = 0.f;
  for (int dp = 0; dp < DKH; ++dp) {
    float v = (float)Vt[(size_t)(h * DKH + dp) * NB + b];
    const float* wrow = &woe[h * DKH + dp][q * 12];
    #pragma unroll
    for (int d = 0; d < 12; ++d) acc[d] += v * wrow[d];
  }
  #pragma unroll
  for (int d = 0; d < 12; ++d)
    VWt[(size_t)(h * DKH + q * 12 + d) * NB + b] = (__bf16)acc[d];
}

// ---------------- fused MFMA attention: wave-private global_load_lds staging ----------------
// grid = ns * 512 blocks x 256 threads. Wave = head h. m == 0 fixed reference.
// K/VW tiles staged to LDS via global_load_lds (no VGPR round-trip -> all 7 stage
// issues in flight in ONE latency window). XOR-swizzled via pre-swizzled global
// source (m173): K slot^=(row&7), VW slot^=((row>>1)&3) -> conflict-free ds_read_b128.
// Wave reads only its own head's rows -> staging is wave-private, ZERO barriers.
// Counted vmcnt(4) (T4): stages drained, W(t+1) prefetch stays in flight.
template<int MMODE>
__global__ __launch_bounds__(256, 4) void attn_kernel(
    const __bf16* __restrict__ Qb, const __bf16* __restrict__ Kb, const __bf16* __restrict__ VWt,
    const float* __restrict__ weight, const void* __restrict__ maskp,
    const int* __restrict__ maskflag, const float* __restrict__ MwG,
    float* __restrict__ part, int tps)
{
  if (*maskflag != MMODE) return;   // wrong-mode instance: early out (grid-uniform)

  __shared__ __align__(16) __bf16 Kl[4 * 32 * 64];   // 16 KB: [h][row 0..31][64e=128B], swizzled
  __shared__ __align__(16) __bf16 VWl[192 * 32];     // 12 KB: [row 0..191][32e=64B], swizzled
  __shared__ __bf16 Ss[4][16][40];                   // P staging (unchanged)

  const int t = threadIdx.x;
  const int lane = t & 63;
  const int h = t >> 6;
  const int c = lane & 15;          // actor col
  const int g = lane >> 4;
  const int g8 = g * 8;
  const int s = blockIdx.x >> 9;    // split
  const int a0 = (blockIdx.x & 511) * TA;
  const int tile0 = s * tps;
  const int tend = tile0 + tps;

  const unsigned char* m8 = (const unsigned char*)maskp;
  const float* mfp = (const float*)maskp;
  const int* m32 = (const int*)maskp;

  // Q fragment (B-operand): col a = c, k contiguous
  const __bf16* qp = Qb + ((size_t)(a0 + c) * NH + h) * 64 + g8;
  const bf16x8 qf0 = *(const bf16x8*)qp;
  const bf16x8 qf1 = *(const bf16x8*)(qp + 32);

  const float MwC = MwG[a0 + c];
  float lp = 0.f, Ap = 0.f;
  f32x4 o0 = {0.f,0.f,0.f,0.f}, o1 = {0.f,0.f,0.f,0.f}, o2 = {0.f,0.f,0.f,0.f};

  const size_t wrow = (size_t)(a0 + c) * NB + g * 4;

  // ---- lane-constant staging geometry (source pre-swizzle; dest linear) ----
  // K: chunk i covers rows i*8+(lane>>3); slot = lane&7; swz = slot ^ (row&7)
  const int kswz = 8 * ((lane & 7) ^ ((lane >> 3) & 7));        // elements
  // VW: chunk j covers rows h*48+j*16+(lane>>2); slot = lane&3; swz = slot ^ ((row>>1)&3)
  const int vswz = 8 * ((lane & 3) ^ ((lane >> 3) & 3));        // elements
  const size_t kgrow = (size_t)h * NB + (lane >> 3);            // + b0 + i*8 per tile
  const size_t vgrow = (size_t)(h * 48 + (lane >> 2)) * NB;     // + b0 per tile
  __bf16* klw = Kl + h * 2048;      // wave's K region (4 KB)
  __bf16* vlw = VWl + h * 1536;     // wave's VW region (3 KB)

  // ---- read-side swizzled fragment offsets (lane-constant) ----
  const int swk  = 8 * (g ^ (c & 7));
  const int swk4 = 8 * ((g | 4) ^ (c & 7));
  const int swv  = 8 * (g ^ ((c >> 1) & 3));
  const __bf16* klr = Kl + h * 2048 + c * 64;
  const __bf16* vlr = VWl + (h * 48 + c) * 32 + swv;

  // ---- raw W prefetch slots (mode-specialized) ----
  float4 nw0, nw1;
  int nmx, nmy;          // mode 1
  int4 nmA, nmB;         // modes 0, 2
  {
    size_t gi = wrow + (size_t)tile0 * TB;
    nw0 = *(const float4*)(weight + gi);
    nw1 = *(const float4*)(weight + gi + 16);
    if constexpr (MMODE == 1)      { nmx = *(const int*)(m8 + gi); nmy = *(const int*)(m8 + gi + 16); }
    else if constexpr (MMODE == 2) { nmA = *(const int4*)(mfp + gi); nmB = *(const int4*)(mfp + gi + 16); }
    else                           { nmA = *(const int4*)(m32 + gi); nmB = *(const int4*)(m32 + gi + 16); }
  }

  for (int tile = tile0; tile < tend; ++tile) {
    const int b0 = tile * TB;

    // [1] stage K (4) + VW (3) for THIS tile -- async, no VGPR destinations.
    //     (prev tile's ds_reads already lgkm-drained by its MFMA consumption)
    {
      const __bf16* kg = Kb + (kgrow + b0) * 64 + kswz;
      GLDS(kg,            klw);
      GLDS(kg + 8 * 64,   klw + 512);
      GLDS(kg + 16 * 64,  klw + 1024);
      GLDS(kg + 24 * 64,  klw + 1536);
      const __bf16* vg = VWt + vgrow + b0 + vswz;
      GLDS(vg,            vlw);
      GLDS(vg + 16 * NB,  vlw + 512);
      GLDS(vg + 32 * NB,  vlw + 1024);
    }
    __builtin_amdgcn_sched_barrier(0);

    // [2] convert W(t) (its 4 loads are front-of-queue; compiler waits just them)
    float wv[8];
    if constexpr (MMODE == 1) {
      unsigned ua = (unsigned)nmx, ub = (unsigned)nmy;
      wv[0] = (ua & 0xffu)         ? nw0.x : -NEGBIG;
      wv[1] = ((ua >> 8) & 0xffu)  ? nw0.y : -NEGBIG;
      wv[2] = ((ua >> 16) & 0xffu) ? nw0.z : -NEGBIG;
      wv[3] = (ua >> 24)           ? nw0.w : -NEGBIG;
      wv[4] = (ub & 0xffu)         ? nw1.x : -NEGBIG;
      wv[5] = ((ub >> 8) & 0xffu)  ? nw1.y : -NEGBIG;
      wv[6] = ((ub >> 16) & 0xffu) ? nw1.z : -NEGBIG;
      wv[7] = (ub >> 24)           ? nw1.w : -NEGBIG;
    } else if constexpr (MMODE == 2) {
      wv[0] = (((unsigned)nmA.x << 1) != 0u) ? nw0.x : -NEGBIG;
      wv[1] = (((unsigned)nmA.y << 1) != 0u) ? nw0.y : -NEGBIG;
      wv[2] = (((unsigned)nmA.z << 1) != 0u) ? nw0.z : -NEGBIG;
      wv[3] = (((unsigned)nmA.w << 1) != 0u) ? nw0.w : -NEGBIG;
      wv[4] = (((unsigned)nmB.x << 1) != 0u) ? nw1.x : -NEGBIG;
      wv[5] = (((unsigned)nmB.y << 1) != 0u) ? nw1.y : -NEGBIG;
      wv[6] = (((unsigned)nmB.z << 1) != 0u) ? nw1.z : -NEGBIG;
      wv[7] = (((unsigned)nmB.w << 1) != 0u) ? nw1.w : -NEGBIG;
    } else {
      wv[0] = nmA.x ? nw0.x : -NEGBIG;
      wv[1] = nmA.y ? nw0.y : -NEGBIG;
      wv[2] = nmA.z ? nw0.z : -NEGBIG;
      wv[3] = nmA.w ? nw0.w : -NEGBIG;
      wv[4] = nmB.x ? nw1.x : -NEGBIG;
      wv[5] = nmB.y ? nw1.y : -NEGBIG;
      wv[6] = nmB.z ? nw1.z : -NEGBIG;
      wv[7] = nmB.w ? nw1.w : -NEGBIG;
    }
    __builtin_amdgcn_sched_barrier(0);

    // [3] issue W(t+1) raws (behind stages in FIFO)
    {
      int tn = (tile + 1 < tend) ? tile + 1 : tile;
      size_t gi = wrow + (size_t)tn * TB;
      nw0 = *(const float4*)(weight + gi);
      nw1 = *(const float4*)(weight + gi + 16);
      if constexpr (MMODE == 1)      { nmx = *(const int*)(m8 + gi); nmy = *(const int*)(m8 + gi + 16); }
      else if constexpr (MMODE == 2) { nmA = *(const int4*)(mfp + gi); nmB = *(const int4*)(mfp + gi + 16); }
      else                           { nmA = *(const int4*)(m32 + gi); nmB = *(const int4*)(m32 + gi + 16); }
    }
    __builtin_amdgcn_sched_barrier(0);

    // [4] counted wait: drain the 7 stages, leave W(t+1)'s 4 loads in flight
    asm volatile("s_waitcnt vmcnt(4)" ::: "memory");
    __builtin_amdgcn_sched_barrier(0);

    // [5] fragments from LDS (swizzled, conflict-free) + compute
    bf16x8 kA0 = *(const bf16x8*)(klr + swk);
    bf16x8 kA1 = *(const bf16x8*)(klr + swk4);
    bf16x8 kB0 = *(const bf16x8*)(klr + 16 * 64 + swk);
    bf16x8 kB1 = *(const bf16x8*)(klr + 16 * 64 + swk4);
    bf16x8 vf0 = *(const bf16x8*)vlr;
    bf16x8 vf1 = *(const bf16x8*)(vlr + 16 * 32);
    bf16x8 vf2 = *(const bf16x8*)(vlr + 32 * 32);

    f32x4 acc0, acc1;
    #pragma unroll
    for (int j = 0; j < 4; ++j) { acc0[j] = wv[j] * INVSCALE; acc1[j] = wv[4 + j] * INVSCALE; }
    acc0 = MFMA16(kA0, qf0, acc0);
    acc0 = MFMA16(kA1, qf1, acc0);
    acc1 = MFMA16(kB0, qf0, acc1);
    acc1 = MFMA16(kB1, qf1, acc1);

    float p[8];
    #pragma unroll
    for (int j = 0; j < 4; ++j) {
      float s0 = acc0[j] * SCALE, s1 = acc1[j] * SCALE;
      float p0 = __expf(s0), p1 = __expf(s1);
      lp += p0 + p1;
      Ap += __expf(s0 + wv[j] - MwC) + __expf(s1 + wv[4 + j] - MwC);
      p[j] = p0; p[4 + j] = p1;
    }

    #pragma unroll
    for (int i = 0; i < 4; ++i) {
      Ss[h][c][g * 4 + i]      = (__bf16)p[i];
      Ss[h][c][16 + g * 4 + i] = (__bf16)p[4 + i];
    }
    __builtin_amdgcn_sched_barrier(0);
    bf16x8 pb = *(const bf16x8*)&Ss[h][c][g8];

    o0 = MFMA16(vf0, pb, o0);
    o1 = MFMA16(vf1, pb, o1);
    o2 = MFMA16(vf2, pb, o2);
  }

  // ---- one wave-reduce at the end; write partial record ----
  float l = rsumg(lp);
  float A = rsumg(Ap);
  float* pr = part + ((size_t)s * NA + a0 + c) * PREC;
  #pragma unroll
  for (int j = 0; j < 4; ++j) {
    pr[h * 48 + g * 4 + j]      = o0[j];
    pr[h * 48 + 16 + g * 4 + j] = o1[j];
    pr[h * 48 + 32 + g * 4 + j] = o2[j];
  }
  if (g == 0) {
    pr[192 + h] = l;
    pr[196 + h] = A;
  }
}

// ---------------- merge splits: plain sums (shared m == 0 reference) ----------------
__global__ __launch_bounds__(256) void merge_kernel(
    const float* __restrict__ part, const float* __restrict__ LwG,
    const float* __restrict__ boe, float* __restrict__ out, int ns)
{
  __shared__ float fls[32][NH];      // 1/l per (a,h)
  __shared__ float infl[32][NH];
  const int t = threadIdx.x;
  const int a0 = blockIdx.x * 32;

  if (t < 128) {
    int a = t >> 2, hh = t & 3;
    const float* rec = part + (size_t)(a0 + a) * PREC;
    float lst = 0.f, As = 0.f;
    for (int s = 0; s < ns; ++s) {
      const float* r = rec + (size_t)s * NA * PREC;
      lst += r[192 + hh];
      As  += r[196 + hh];
    }
    float li = 1.f / lst;
    fls[a][hh] = li;
    infl[a][hh] = As * li;
  }
  __syncthreads();
  if (t < 32)
    out[(size_t)(a0 + t) * 49 + 48] =
        (infl[t][0] + infl[t][1] + infl[t][2] + infl[t][3]) / (4.f * LwG[a0 + t]);
  for (int i = t; i < 32 * DKH; i += 256) {
    int a = i / DKH, dd = i - a * DKH;
    float acc = boe[dd];
    const float* rec = part + (size_t)(a0 + a) * PREC;
    for (int s = 0; s < ns; ++s) {
      const float* r = rec + (size_t)s * NA * PREC;
      #pragma unroll
      for (int hh = 0; hh < NH; ++hh)
        acc += fls[a][hh] * r[hh * 48 + dd];
    }
    out[(size_t)(a0 + a) * 49 + dd] = acc;
  }
}

extern "C" void kernel_launch(void* const* d_in, const int* in_sizes, int n_in,
                              void* d_out, int out_size, void* d_ws, size_t ws_size,
                              hipStream_t stream) {
  const float* a_z    = (const float*)d_in[0];
  const float* bv_z   = (const float*)d_in[1];
  const float* weight = (const float*)d_in[2];
  const void*  maskp  = d_in[3];
  const float* Wq = (const float*)d_in[4];
  const float* Wk = (const float*)d_in[5];
  const float* Wv = (const float*)d_in[6];
  const float* Wo = (const float*)d_in[7];
  const float* bq = (const float*)d_in[8];
  const float* bk = (const float*)d_in[9];
  const float* bvb = (const float*)d_in[10];
  const float* bo = (const float*)d_in[11];

  __bf16* Qb  = (__bf16*)d_ws;                      // [NA][4][64]
  __bf16* Kb  = Qb + (size_t)NA * 256;              // [4][NB][64]
  __bf16* Vtg = Kb + (size_t)4 * NB * 64;           // [192][NB]
  __bf16* VWt = Vtg + (size_t)DIM * NB;             // [192][NB]
  float* WoeT = (float*)(VWt + (size_t)DIM * NB);   // [192][48]
  float* boe  = WoeT + DIM * DKH;
  int*  mflag = (int*)(boe + 64);
  float* MwG  = (float*)(mflag + 64);               // [NA]
  float* LwG  = MwG + NA;                           // [NA]
  float* part = LwG + NA;                           // [ns][NA][200]

  size_t base = (size_t)((char*)(part) - (char*)d_ws);
  int ns = (ws_size >= base + (size_t)4 * NA * PREC * 4) ? 4 : 2;
  int tps = (NB / TB) / ns;

  prep_kernel<<<3621, 256, 0, stream>>>(a_z, bv_z, Wq, Wk, Wv, bq, bk, bvb, Wo, bo,
                                        weight, maskp, Qb, Kb, Vtg, WoeT, boe, mflag,
                                        MwG, LwG);
  vw_kernel<<<NB / 16, 256, 0, stream>>>(Vtg, WoeT, VWt);
  attn_kernel<1><<<ns * 512, 256, 0, stream>>>(Qb, Kb, VWt, weight, maskp, mflag, MwG, part, tps);
  attn_kernel<0><<<ns * 512, 256, 0, stream>>>(Qb, Kb, VWt, weight, maskp, mflag, MwG, part, tps);
  attn_kernel<2><<<ns * 512, 256, 0, stream>>>(Qb, Kb, VWt, weight, maskp, mflag, MwG, part, tps);
  merge_kernel<<<NA / 32, 256, 0, stream>>>(part, LwG, boe, (float*)d_out, ns);
}

// Round 15
// 175.857 us; speedup vs baseline: 1.4764x; 1.0005x over previous
//
#include <hip/hip_runtime.h>
#include <hip/hip_bf16.h>

#define NA 8192
#define NB 2048
#define DIM 192
#define NH 4
#define DKH 48
#define TA 16
#define TB 32
#define PREC 200                       // floats per partial record (192 T + 4 l + 4 A)
#define SCALE 0.14433756729740643f     // 1/sqrt(48)
#define INVSCALE 6.928203230275509f    // sqrt(48)
#define NEGBIG 1e30f

typedef __bf16 bf16x8 __attribute__((ext_vector_type(8)));
typedef float f32x4 __attribute__((ext_vector_type(4)));

#define MFMA16(a, b, c) __builtin_amdgcn_mfma_f32_16x16x32_bf16(a, b, c, 0, 0, 0)

// async global->LDS, 16B per lane, dest = ldsbase + lane*16 (wave-uniform base)
#define GLDS(gp, lp)                                                      \
  __builtin_amdgcn_global_load_lds(                                       \
      (__attribute__((address_space(1))) void*)(const void*)(gp),         \
      (__attribute__((address_space(3))) void*)(void*)(lp), 16, 0, 0)

__device__ __forceinline__ float rsumg(float v) {
  v += __shfl_xor(v, 16, 64);
  v += __shfl_xor(v, 32, 64);
  return v;
}

// ---------------- fused prep: proj + maskdetect + woe + wstats ----------------
__global__ __launch_bounds__(256) void prep_kernel(
    const float* __restrict__ a_z, const float* __restrict__ bv_z,
    const float* __restrict__ Wq, const float* __restrict__ Wk, const float* __restrict__ Wv,
    const float* __restrict__ bq, const float* __restrict__ bk, const float* __restrict__ bvb,
    const float* __restrict__ Wo, const float* __restrict__ bo,
    const float* __restrict__ weight, const void* __restrict__ maskp,
    __bf16* __restrict__ Qo, __bf16* __restrict__ Ko, __bf16* __restrict__ Vo,
    float* __restrict__ WoeT, float* __restrict__ boe, int* __restrict__ mflag,
    float* __restrict__ MwG, float* __restrict__ LwG)
{
  const int blk = blockIdx.x;
  const int t = threadIdx.x;

  if (blk < 1536) {
    // ================= proj =================
    __shared__ float xs[8][DIM];
    const float* src; const float* W; const float* bias; int row0; int which;
    if (blk < 1024)      { src = a_z;  W = Wq; bias = bq;  row0 = blk * 8;          which = 0; }
    else if (blk < 1280) { src = bv_z; W = Wk; bias = bk;  row0 = (blk - 1024) * 8; which = 1; }
    else                 { src = bv_z; W = Wv; bias = bvb; row0 = (blk - 1280) * 8; which = 2; }
    for (int i = t; i < 8 * 48; i += 256) {
      int r = i / 48, c = i % 48;
      ((float4*)xs[r])[c] = ((const float4*)(src + (size_t)(row0 + r) * DIM))[c];
    }
    __syncthreads();
    if (t < 192) {
      float acc[8];
      float bb = bias[t];
      #pragma unroll
      for (int r = 0; r < 8; ++r) acc[r] = bb;
      const float4* wr = (const float4*)(W + (size_t)t * DIM);
      for (int c = 0; c < 48; ++c) {
        float4 w = wr[c];
        #pragma unroll
        for (int r = 0; r < 8; ++r) {
          float4 x = ((const float4*)xs[r])[c];
          acc[r] += w.x * x.x + w.y * x.y + w.z * x.z + w.w * x.w;
        }
      }
      int h = t / 48, dd = t % 48;
      if (which == 0) {
        #pragma unroll
        for (int r = 0; r < 8; ++r)
          Qo[((size_t)(row0 + r) * 4 + h) * 64 + dd] = (__bf16)acc[r];
      } else if (which == 1) {
        #pragma unroll
        for (int r = 0; r < 8; ++r)
          Ko[((size_t)h * NB + row0 + r) * 64 + dd] = (__bf16)acc[r];
      } else {
        bf16x8 pk;
        #pragma unroll
        for (int r = 0; r < 8; ++r) pk[r] = (__bf16)acc[r];
        *(bf16x8*)(Vo + (size_t)t * NB + row0) = pk;
      }
    }
    if (which == 0) {
      for (int i = t; i < 512; i += 256) {   // zero the K-pad [48,64)
        int r = i >> 6, hh = (i >> 4) & 3, kk = i & 15;
        Qo[((size_t)(row0 + r) * 4 + hh) * 64 + 48 + kk] = (__bf16)0.f;
      }
    } else if (which == 1) {
      for (int i = t; i < 512; i += 256) {
        int r = i >> 6, hh = (i >> 4) & 3, kk = i & 15;
        Ko[((size_t)hh * NB + row0 + r) * 64 + 48 + kk] = (__bf16)0.f;
      }
    }
  } else if (blk == 1536) {
    // ================= mask detect =================
    __shared__ int fl;
    if (t == 0) fl = 0;
    __syncthreads();
    const unsigned int* mw = (const unsigned int*)maskp;
    for (int i = t; i < 1024; i += 256) {
      unsigned int v = mw[i];
      if (v == 0x3F800000u) atomicMax(&fl, 2);
      else if (v > 1u) atomicMax(&fl, 1);
    }
    __syncthreads();
    if (t == 0) *mflag = fl;
  } else if (blk < 1573) {
    // ================= Wo_eff^T =================
    int i = (blk - 1537) * 256 + t;
    if (i < DIM * DKH) {
      int k = i / DKH, d = i % DKH;
      float s = 0.25f * (Wo[(size_t)d * DIM + k] + Wo[(size_t)(d + 48) * DIM + k] +
                         Wo[(size_t)(d + 96) * DIM + k] + Wo[(size_t)(d + 144) * DIM + k]);
      WoeT[k * DKH + d] = s;
    }
    if (i < DKH) boe[i] = 0.25f * (bo[i] + bo[i + 48] + bo[i + 96] + bo[i + 144]);
  } else {
    // ================= wstats (inline mask detect) =================
    __shared__ int fl;
    if (t == 0) fl = 0;
    __syncthreads();
    {
      const unsigned int* mw = (const unsigned int*)maskp;
      for (int i = t; i < 1024; i += 256) {
        unsigned int v = mw[i];
        if (v == 0x3F800000u) atomicMax(&fl, 2);
        else if (v > 1u) atomicMax(&fl, 1);
      }
    }
    __syncthreads();
    const int mmode = fl;
    const int lane = t & 63;
    const int a = (blk - 1573) * 4 + (t >> 6);
    const float* wr = weight + (size_t)a * NB;
    const unsigned char* m8 = (const unsigned char*)maskp + (size_t)a * NB;
    const float* mf = (const float*)maskp + (size_t)a * NB;
    const int* m32 = (const int*)maskp + (size_t)a * NB;

    float mloc = -NEGBIG, sloc = 0.f;
    for (int it = 0; it < 8; ++it) {
      int idx = it * 256 + lane * 4;
      float4 w4 = *(const float4*)(wr + idx);
      bool ok0, ok1, ok2, ok3;
      if (mmode == 1) {
        unsigned mm = *(const unsigned*)(m8 + idx);
        ok0 = mm & 0xffu; ok1 = (mm >> 8) & 0xffu; ok2 = (mm >> 16) & 0xffu; ok3 = mm >> 24;
      } else if (mmode == 2) {
        float4 mv = *(const float4*)(mf + idx);
        ok0 = mv.x != 0.f; ok1 = mv.y != 0.f; ok2 = mv.z != 0.f; ok3 = mv.w != 0.f;
      } else {
        int4 mv = *(const int4*)(m32 + idx);
        ok0 = mv.x; ok1 = mv.y; ok2 = mv.z; ok3 = mv.w;
      }
      float v0 = ok0 ? w4.x : -NEGBIG;
      float v1 = ok1 ? w4.y : -NEGBIG;
      float v2 = ok2 ? w4.z : -NEGBIG;
      float v3 = ok3 ? w4.w : -NEGBIG;
      float mt = fmaxf(fmaxf(v0, v1), fmaxf(v2, v3));
      float mn = fmaxf(mloc, mt);
      float sc = __expf(mloc - mn);
      float e0 = (v0 > -1e29f) ? __expf(v0 - mn) : 0.f;
      float e1 = (v1 > -1e29f) ? __expf(v1 - mn) : 0.f;
      float e2 = (v2 > -1e29f) ? __expf(v2 - mn) : 0.f;
      float e3 = (v3 > -1e29f) ? __expf(v3 - mn) : 0.f;
      sloc = sloc * sc + (e0 + e1) + (e2 + e3);
      mloc = mn;
    }
    float mfin = mloc;
    #pragma unroll
    for (int off = 1; off < 64; off <<= 1) mfin = fmaxf(mfin, __shfl_xor(mfin, off, 64));
    float sadj = sloc * __expf(mloc - mfin);
    #pragma unroll
    for (int off = 1; off < 64; off <<= 1) sadj += __shfl_xor(sadj, off, 64);
    if (lane == 0) { MwG[a] = mfin; LwG[a] = sadj; }
  }
}

// ---------------- VW = per-head V @ Woe_h ----------------
__global__ __launch_bounds__(256) void vw_kernel(
    const __bf16* __restrict__ Vt, const float* __restrict__ WoeT, __bf16* __restrict__ VWt)
{
  __shared__ float woe[DIM][DKH];
  const int t = threadIdx.x;
  for (int i = t; i < DIM * DKH / 4; i += 256)
    ((float4*)&woe[0][0])[i] = ((const float4*)WoeT)[i];
  __syncthreads();
  const int b = blockIdx.x * 16 + (t & 15);
  const int grp = t >> 4;
  const int h = grp >> 2;
  const int q = grp & 3;
  float acc[12];
  #pragma unroll
  for (int d = 0; d < 12; ++d) acc[d] = 0.f;
  for (int dp = 0; dp < DKH; ++dp) {
    float v = (float)Vt[(size_t)(h * DKH + dp) * NB + b];
    const float* wrow = &woe[h * DKH + dp][q * 12];
    #pragma unroll
    for (int d = 0; d < 12; ++d) acc[d] += v * wrow[d];
  }
  #pragma unroll
  for (int d = 0; d < 12; ++d)
    VWt[(size_t)(h * DKH + q * 12 + d) * NB + b] = (__bf16)acc[d];
}

// ---------------- fused MFMA attention: double-buffered K, pipelined staging ----------------
// grid = ns * 512 blocks x 256 threads. Wave = head h. m == 0 fixed reference.
// Pipeline per tile (wave-private, ZERO barriers):
//   [A] stage VW(t) (3 GLDS)           -> consumed at end of this body (~250 cy flight)
//   [B] stage K(t+1) (4 GLDS) -> buf^1 -> consumed next body (full-body flight)
//   [C] convert W(t) (compiler auto-wait drains W(t)+K(t), both issued last body)
//   [D] issue W(t+1) raw loads          -> full-body flight
//   [E] QK from Kbuf[cur] (already drained by [C]'s wait)
//   [F] exp + P->Ss
//   [G] vmcnt(8) (drain VW(t); K(t+1)+W(t+1) stay in flight) -> PV
// No wait in the loop ever drains the prefetches (T4: counted, never 0).
template<int MMODE>
__global__ __launch_bounds__(256, 4) void attn_kernel(
    const __bf16* __restrict__ Qb, const __bf16* __restrict__ Kb, const __bf16* __restrict__ VWt,
    const float* __restrict__ weight, const void* __restrict__ maskp,
    const int* __restrict__ maskflag, const float* __restrict__ MwG,
    float* __restrict__ part, int tps)
{
  if (*maskflag != MMODE) return;   // wrong-mode instance: early out (grid-uniform)

  __shared__ __align__(16) __bf16 Kl[2 * 4 * 32 * 64];   // 32 KB: double-buffered K
  __shared__ __align__(16) __bf16 VWl[192 * 32];         // 12 KB
  __shared__ __bf16 Ss[4][16][40];                       // 5 KB P staging

  const int t = threadIdx.x;
  const int lane = t & 63;
  const int h = t >> 6;
  const int c = lane & 15;          // actor col
  const int g = lane >> 4;
  const int g8 = g * 8;
  const int s = blockIdx.x >> 9;    // split
  const int a0 = (blockIdx.x & 511) * TA;
  const int tile0 = s * tps;
  const int tend = tile0 + tps;

  const unsigned char* m8 = (const unsigned char*)maskp;
  const float* mfp = (const float*)maskp;
  const int* m32 = (const int*)maskp;

  // Q fragment (B-operand): col a = c, k contiguous
  const __bf16* qp = Qb + ((size_t)(a0 + c) * NH + h) * 64 + g8;
  const bf16x8 qf0 = *(const bf16x8*)qp;
  const bf16x8 qf1 = *(const bf16x8*)(qp + 32);

  const float MwC = MwG[a0 + c];
  float lp = 0.f, Ap = 0.f;
  f32x4 o0 = {0.f,0.f,0.f,0.f}, o1 = {0.f,0.f,0.f,0.f}, o2 = {0.f,0.f,0.f,0.f};

  const size_t wrow = (size_t)(a0 + c) * NB + g * 4;

  // ---- lane-constant staging geometry (source pre-swizzle; dest linear) ----
  const int kswz = 8 * ((lane & 7) ^ ((lane >> 3) & 7));        // elements
  const int vswz = 8 * ((lane & 3) ^ ((lane >> 3) & 3));        // elements
  const size_t kgrow = (size_t)h * NB + (lane >> 3);            // + b per tile
  const size_t vgrow = (size_t)(h * 48 + (lane >> 2)) * NB;     // + b0 per tile
  __bf16* vlw = VWl + h * 1536;     // wave's VW region (3 KB)

  // ---- read-side swizzled fragment offsets (lane-constant) ----
  const int swk  = 8 * (g ^ (c & 7));
  const int swk4 = 8 * ((g | 4) ^ (c & 7));
  const int swv  = 8 * (g ^ ((c >> 1) & 3));
  const __bf16* vlr = VWl + (h * 48 + c) * 32 + swv;

  // ---- raw W prefetch slots (mode-specialized) ----
  float4 nw0, nw1;
  int nmx, nmy;          // mode 1
  int4 nmA, nmB;         // modes 0, 2

  // ---- prologue: stage K(tile0) into buf0, issue W(tile0). FIFO: [K0 4][W0 4] ----
  {
    const __bf16* kg = Kb + (kgrow + (size_t)tile0 * TB) * 64 + kswz;
    __bf16* klw = Kl + h * 2048;
    GLDS(kg,           klw);
    GLDS(kg + 8 * 64,  klw + 512);
    GLDS(kg + 16 * 64, klw + 1024);
    GLDS(kg + 24 * 64, klw + 1536);
    size_t gi = wrow + (size_t)tile0 * TB;
    nw0 = *(const float4*)(weight + gi);
    nw1 = *(const float4*)(weight + gi + 16);
    if constexpr (MMODE == 1)      { nmx = *(const int*)(m8 + gi); nmy = *(const int*)(m8 + gi + 16); }
    else if constexpr (MMODE == 2) { nmA = *(const int4*)(mfp + gi); nmB = *(const int4*)(mfp + gi + 16); }
    else                           { nmA = *(const int4*)(m32 + gi); nmB = *(const int4*)(m32 + gi + 16); }
  }

  for (int tile = tile0; tile < tend; ++tile) {
    const int b0 = tile * TB;
    const int cur = tile & 1;
    const __bf16* klr = Kl + cur * 8192 + h * 2048 + c * 64;

    // [A] stage VW(t) -- consumed at the END of this body
    {
      const __bf16* vg = VWt + vgrow + b0 + vswz;
      GLDS(vg,           vlw);
      GLDS(vg + 16 * NB, vlw + 512);
      GLDS(vg + 32 * NB, vlw + 1024);
    }
    __builtin_amdgcn_sched_barrier(0);

    // [B] stage K(t+1) into the other buffer (full body of flight)
    {
      int tn = (tile + 1 < tend) ? tile + 1 : tile;   // clamp: restage, unused buf
      const __bf16* kg = Kb + (kgrow + (size_t)tn * TB) * 64 + kswz;
      __bf16* klwN = Kl + (cur ^ 1) * 8192 + h * 2048;
      GLDS(kg,           klwN);
      GLDS(kg + 8 * 64,  klwN + 512);
      GLDS(kg + 16 * 64, klwN + 1024);
      GLDS(kg + 24 * 64, klwN + 1536);
    }
    __builtin_amdgcn_sched_barrier(0);

    // [C] convert W(t): compiler auto-wait drains W(t) (and K(t), older in FIFO)
    float wv[8];
    if constexpr (MMODE == 1) {
      unsigned ua = (unsigned)nmx, ub = (unsigned)nmy;
      wv[0] = (ua & 0xffu)         ? nw0.x : -NEGBIG;
      wv[1] = ((ua >> 8) & 0xffu)  ? nw0.y : -NEGBIG;
      wv[2] = ((ua >> 16) & 0xffu) ? nw0.z : -NEGBIG;
      wv[3] = (ua >> 24)           ? nw0.w : -NEGBIG;
      wv[4] = (ub & 0xffu)         ? nw1.x : -NEGBIG;
      wv[5] = ((ub >> 8) & 0xffu)  ? nw1.y : -NEGBIG;
      wv[6] = ((ub >> 16) & 0xffu) ? nw1.z : -NEGBIG;
      wv[7] = (ub >> 24)           ? nw1.w : -NEGBIG;
    } else if constexpr (MMODE == 2) {
      wv[0] = (((unsigned)nmA.x << 1) != 0u) ? nw0.x : -NEGBIG;
      wv[1] = (((unsigned)nmA.y << 1) != 0u) ? nw0.y : -NEGBIG;
      wv[2] = (((unsigned)nmA.z << 1) != 0u) ? nw0.z : -NEGBIG;
      wv[3] = (((unsigned)nmA.w << 1) != 0u) ? nw0.w : -NEGBIG;
      wv[4] = (((unsigned)nmB.x << 1) != 0u) ? nw1.x : -NEGBIG;
      wv[5] = (((unsigned)nmB.y << 1) != 0u) ? nw1.y : -NEGBIG;
      wv[6] = (((unsigned)nmB.z << 1) != 0u) ? nw1.z : -NEGBIG;
      wv[7] = (((unsigned)nmB.w << 1) != 0u) ? nw1.w : -NEGBIG;
    } else {
      wv[0] = nmA.x ? nw0.x : -NEGBIG;
      wv[1] = nmA.y ? nw0.y : -NEGBIG;
      wv[2] = nmA.z ? nw0.z : -NEGBIG;
      wv[3] = nmA.w ? nw0.w : -NEGBIG;
      wv[4] = nmB.x ? nw1.x : -NEGBIG;
      wv[5] = nmB.y ? nw1.y : -NEGBIG;
      wv[6] = nmB.z ? nw1.z : -NEGBIG;
      wv[7] = nmB.w ? nw1.w : -NEGBIG;
    }
    __builtin_amdgcn_sched_barrier(0);

    // [D] issue W(t+1) raws (behind VW(t), K(t+1) in FIFO; full body of flight)
    {
      int tn = (tile + 1 < tend) ? tile + 1 : tile;
      size_t gi = wrow + (size_t)tn * TB;
      nw0 = *(const float4*)(weight + gi);
      nw1 = *(const float4*)(weight + gi + 16);
      if constexpr (MMODE == 1)      { nmx = *(const int*)(m8 + gi); nmy = *(const int*)(m8 + gi + 16); }
      else if constexpr (MMODE == 2) { nmA = *(const int4*)(mfp + gi); nmB = *(const int4*)(mfp + gi + 16); }
      else                           { nmA = *(const int4*)(m32 + gi); nmB = *(const int4*)(m32 + gi + 16); }
    }
    __builtin_amdgcn_sched_barrier(0);

    // [E] QK from Kbuf[cur] (drained by [C]'s wait; order pinned by sched_barriers)
    bf16x8 kA0 = *(const bf16x8*)(klr + swk);
    bf16x8 kA1 = *(const bf16x8*)(klr + swk4);
    bf16x8 kB0 = *(const bf16x8*)(klr + 16 * 64 + swk);
    bf16x8 kB1 = *(const bf16x8*)(klr + 16 * 64 + swk4);
    f32x4 acc0, acc1;
    #pragma unroll
    for (int j = 0; j < 4; ++j) { acc0[j] = wv[j] * INVSCALE; acc1[j] = wv[4 + j] * INVSCALE; }
    acc0 = MFMA16(kA0, qf0, acc0);
    acc0 = MFMA16(kA1, qf1, acc0);
    acc1 = MFMA16(kB0, qf0, acc1);
    acc1 = MFMA16(kB1, qf1, acc1);

    // [F] p = exp(sv) vs fixed 0 reference; influence inline; P -> Ss
    float p[8];
    #pragma unroll
    for (int j = 0; j < 4; ++j) {
      float s0 = acc0[j] * SCALE, s1 = acc1[j] * SCALE;
      float p0 = __expf(s0), p1 = __expf(s1);
      lp += p0 + p1;
      Ap += __expf(s0 + wv[j] - MwC) + __expf(s1 + wv[4 + j] - MwC);
      p[j] = p0; p[4 + j] = p1;
    }
    #pragma unroll
    for (int i = 0; i < 4; ++i) {
      Ss[h][c][g * 4 + i]      = (__bf16)p[i];
      Ss[h][c][16 + g * 4 + i] = (__bf16)p[4 + i];
    }
    __builtin_amdgcn_sched_barrier(0);
    bf16x8 pb = *(const bf16x8*)&Ss[h][c][g8];

    // [G] drain VW(t) only (leaves K(t+1) 4 + W(t+1) 4 in flight), then PV
    asm volatile("s_waitcnt vmcnt(8)" ::: "memory");
    __builtin_amdgcn_sched_barrier(0);
    bf16x8 vf0 = *(const bf16x8*)vlr;
    bf16x8 vf1 = *(const bf16x8*)(vlr + 16 * 32);
    bf16x8 vf2 = *(const bf16x8*)(vlr + 32 * 32);
    o0 = MFMA16(vf0, pb, o0);
    o1 = MFMA16(vf1, pb, o1);
    o2 = MFMA16(vf2, pb, o2);
  }

  // ---- one wave-reduce at the end; write partial record ----
  float l = rsumg(lp);
  float A = rsumg(Ap);
  float* pr = part + ((size_t)s * NA + a0 + c) * PREC;
  #pragma unroll
  for (int j = 0; j < 4; ++j) {
    pr[h * 48 + g * 4 + j]      = o0[j];
    pr[h * 48 + 16 + g * 4 + j] = o1[j];
    pr[h * 48 + 32 + g * 4 + j] = o2[j];
  }
  if (g == 0) {
    pr[192 + h] = l;
    pr[196 + h] = A;
  }
}

// ---------------- merge splits: plain sums (shared m == 0 reference) ----------------
__global__ __launch_bounds__(256) void merge_kernel(
    const float* __restrict__ part, const float* __restrict__ LwG,
    const float* __restrict__ boe, float* __restrict__ out, int ns)
{
  __shared__ float fls[32][NH];      // 1/l per (a,h)
  __shared__ float infl[32][NH];
  const int t = threadIdx.x;
  const int a0 = blockIdx.x * 32;

  if (t < 128) {
    int a = t >> 2, hh = t & 3;
    const float* rec = part + (size_t)(a0 + a) * PREC;
    float lst = 0.f, As = 0.f;
    for (int s = 0; s < ns; ++s) {
      const float* r = rec + (size_t)s * NA * PREC;
      lst += r[192 + hh];
      As  += r[196 + hh];
    }
    float li = 1.f / lst;
    fls[a][hh] = li;
    infl[a][hh] = As * li;
  }
  __syncthreads();
  if (t < 32)
    out[(size_t)(a0 + t) * 49 + 48] =
        (infl[t][0] + infl[t][1] + infl[t][2] + infl[t][3]) / (4.f * LwG[a0 + t]);
  for (int i = t; i < 32 * DKH; i += 256) {
    int a = i / DKH, dd = i - a * DKH;
    float acc = boe[dd];
    const float* rec = part + (size_t)(a0 + a) * PREC;
    for (int s = 0; s < ns; ++s) {
      const float* r = rec + (size_t)s * NA * PREC;
      #pragma unroll
      for (int hh = 0; hh < NH; ++hh)
        acc += fls[a][hh] * r[hh * 48 + dd];
    }
    out[(size_t)(a0 + a) * 49 + dd] = acc;
  }
}

extern "C" void kernel_launch(void* const* d_in, const int* in_sizes, int n_in,
                              void* d_out, int out_size, void* d_ws, size_t ws_size,
                              hipStream_t stream) {
  const float* a_z    = (const float*)d_in[0];
  const float* bv_z   = (const float*)d_in[1];
  const float* weight = (const float*)d_in[2];
  const void*  maskp  = d_in[3];
  const float* Wq = (const float*)d_in[4];
  const float* Wk = (const float*)d_in[5];
  const float* Wv = (const float*)d_in[6];
  const float* Wo = (const float*)d_in[7];
  const float* bq = (const float*)d_in[8];
  const float* bk = (const float*)d_in[9];
  const float* bvb = (const float*)d_in[10];
  const float* bo = (const float*)d_in[11];

  __bf16* Qb  = (__bf16*)d_ws;                      // [NA][4][64]
  __bf16* Kb  = Qb + (size_t)NA * 256;              // [4][NB][64]
  __bf16* Vtg = Kb + (size_t)4 * NB * 64;           // [192][NB]
  __bf16* VWt = Vtg + (size_t)DIM * NB;             // [192][NB]
  float* WoeT = (float*)(VWt + (size_t)DIM * NB);   // [192][48]
  float* boe  = WoeT + DIM * DKH;
  int*  mflag = (int*)(boe + 64);
  float* MwG  = (float*)(mflag + 64);               // [NA]
  float* LwG  = MwG + NA;                           // [NA]
  float* part = LwG + NA;                           // [ns][NA][200]

  size_t base = (size_t)((char*)(part) - (char*)d_ws);
  int ns = (ws_size >= base + (size_t)4 * NA * PREC * 4) ? 4 : 2;
  int tps = (NB / TB) / ns;

  prep_kernel<<<3621, 256, 0, stream>>>(a_z, bv_z, Wq, Wk, Wv, bq, bk, bvb, Wo, bo,
                                        weight, maskp, Qb, Kb, Vtg, WoeT, boe, mflag,
                                        MwG, LwG);
  vw_kernel<<<NB / 16, 256, 0, stream>>>(Vtg, WoeT, VWt);
  attn_kernel<1><<<ns * 512, 256, 0, stream>>>(Qb, Kb, VWt, weight, maskp, mflag, MwG, part, tps);
  attn_kernel<0><<<ns * 512, 256, 0, stream>>>(Qb, Kb, VWt, weight, maskp, mflag, MwG, part, tps);
  attn_kernel<2><<<ns * 512, 256, 0, stream>>>(Qb, Kb, VWt, weight, maskp, mflag, MwG, part, tps);
  merge_kernel<<<NA / 32, 256, 0, stream>>>(part, LwG, boe, (float*)d_out, ns);
}

// Round 16
// 166.010 us; speedup vs baseline: 1.5640x; 1.0593x over previous
//
#include <hip/hip_runtime.h>
#include <hip/hip_bf16.h>

#define NA 8192
#define NB 2048
#define DIM 192
#define NH 4
#define DKH 48
#define TA 16
#define TB 32
#define PREC 204                       // floats per partial record (192 T + 4 l + 4 A + 1 Lw + pad)
#define SCALE 0.14433756729740643f     // 1/sqrt(48)
#define NEGBIG 1e30f

typedef __bf16 bf16x8 __attribute__((ext_vector_type(8)));
typedef float f32x4 __attribute__((ext_vector_type(4)));

#define MFMA16(a, b, c) __builtin_amdgcn_mfma_f32_16x16x32_bf16(a, b, c, 0, 0, 0)

// async global->LDS, 16B per lane, dest = ldsbase + lane*16 (wave-uniform base)
#define GLDS(gp, lp)                                                      \
  __builtin_amdgcn_global_load_lds(                                       \
      (__attribute__((address_space(1))) void*)(const void*)(gp),         \
      (__attribute__((address_space(3))) void*)(void*)(lp), 16, 0, 0)

__device__ __forceinline__ float rsumg(float v) {
  v += __shfl_xor(v, 16, 64);
  v += __shfl_xor(v, 32, 64);
  return v;
}

// ---------------- fused prep: proj + maskdetect + woe ----------------
// blocks [0,1536): Q/K/V projections; 1536: mask detect; [1537,1573): Wo_eff^T
__global__ __launch_bounds__(256) void prep_kernel(
    const float* __restrict__ a_z, const float* __restrict__ bv_z,
    const float* __restrict__ Wq, const float* __restrict__ Wk, const float* __restrict__ Wv,
    const float* __restrict__ bq, const float* __restrict__ bk, const float* __restrict__ bvb,
    const float* __restrict__ Wo, const float* __restrict__ bo,
    const void* __restrict__ maskp,
    __bf16* __restrict__ Qo, __bf16* __restrict__ Ko, __bf16* __restrict__ Vo,
    float* __restrict__ WoeT, float* __restrict__ boe, int* __restrict__ mflag)
{
  const int blk = blockIdx.x;
  const int t = threadIdx.x;

  if (blk < 1536) {
    // ================= proj =================
    __shared__ float xs[8][DIM];
    const float* src; const float* W; const float* bias; int row0; int which;
    if (blk < 1024)      { src = a_z;  W = Wq; bias = bq;  row0 = blk * 8;          which = 0; }
    else if (blk < 1280) { src = bv_z; W = Wk; bias = bk;  row0 = (blk - 1024) * 8; which = 1; }
    else                 { src = bv_z; W = Wv; bias = bvb; row0 = (blk - 1280) * 8; which = 2; }
    for (int i = t; i < 8 * 48; i += 256) {
      int r = i / 48, c = i % 48;
      ((float4*)xs[r])[c] = ((const float4*)(src + (size_t)(row0 + r) * DIM))[c];
    }
    __syncthreads();
    if (t < 192) {
      float acc[8];
      float bb = bias[t];
      #pragma unroll
      for (int r = 0; r < 8; ++r) acc[r] = bb;
      const float4* wr = (const float4*)(W + (size_t)t * DIM);
      for (int c = 0; c < 48; ++c) {
        float4 w = wr[c];
        #pragma unroll
        for (int r = 0; r < 8; ++r) {
          float4 x = ((const float4*)xs[r])[c];
          acc[r] += w.x * x.x + w.y * x.y + w.z * x.z + w.w * x.w;
        }
      }
      int h = t / 48, dd = t % 48;
      if (which == 0) {
        #pragma unroll
        for (int r = 0; r < 8; ++r)
          Qo[((size_t)(row0 + r) * 4 + h) * 64 + dd] = (__bf16)acc[r];
      } else if (which == 1) {
        #pragma unroll
        for (int r = 0; r < 8; ++r)
          Ko[((size_t)h * NB + row0 + r) * 64 + dd] = (__bf16)acc[r];
      } else {
        bf16x8 pk;
        #pragma unroll
        for (int r = 0; r < 8; ++r) pk[r] = (__bf16)acc[r];
        *(bf16x8*)(Vo + (size_t)t * NB + row0) = pk;
      }
    }
    if (which == 0) {
      for (int i = t; i < 512; i += 256) {   // zero the K-pad [48,64)
        int r = i >> 6, hh = (i >> 4) & 3, kk = i & 15;
        Qo[((size_t)(row0 + r) * 4 + hh) * 64 + 48 + kk] = (__bf16)0.f;
      }
    } else if (which == 1) {
      for (int i = t; i < 512; i += 256) {
        int r = i >> 6, hh = (i >> 4) & 3, kk = i & 15;
        Ko[((size_t)hh * NB + row0 + r) * 64 + 48 + kk] = (__bf16)0.f;
      }
    }
  } else if (blk == 1536) {
    // ================= mask detect =================
    __shared__ int fl;
    if (t == 0) fl = 0;
    __syncthreads();
    const unsigned int* mw = (const unsigned int*)maskp;
    for (int i = t; i < 1024; i += 256) {
      unsigned int v = mw[i];
      if (v == 0x3F800000u) atomicMax(&fl, 2);
      else if (v > 1u) atomicMax(&fl, 1);
    }
    __syncthreads();
    if (t == 0) *mflag = fl;
  } else {
    // ================= Wo_eff^T =================
    int i = (blk - 1537) * 256 + t;
    if (i < DIM * DKH) {
      int k = i / DKH, d = i % DKH;
      float s = 0.25f * (Wo[(size_t)d * DIM + k] + Wo[(size_t)(d + 48) * DIM + k] +
                         Wo[(size_t)(d + 96) * DIM + k] + Wo[(size_t)(d + 144) * DIM + k]);
      WoeT[k * DKH + d] = s;
    }
    if (i < DKH) boe[i] = 0.25f * (bo[i] + bo[i + 48] + bo[i + 96] + bo[i + 144]);
  }
}

// ---------------- VW = per-head V @ Woe_h ----------------
__global__ __launch_bounds__(256) void vw_kernel(
    const __bf16* __restrict__ Vt, const float* __restrict__ WoeT, __bf16* __restrict__ VWt)
{
  __shared__ float woe[DIM][DKH];
  const int t = threadIdx.x;
  for (int i = t; i < DIM * DKH / 4; i += 256)
    ((float4*)&woe[0][0])[i] = ((const float4*)WoeT)[i];
  __syncthreads();
  const int b = blockIdx.x * 16 + (t & 15);
  const int grp = t >> 4;
  const int h = grp >> 2;
  const int q = grp & 3;
  float acc[12];
  #pragma unroll
  for (int d = 0; d < 12; ++d) acc[d] = 0.f;
  for (int dp = 0; dp < DKH; ++dp) {
    float v = (float)Vt[(size_t)(h * DKH + dp) * NB + b];
    const float* wrow = &woe[h * DKH + dp][q * 12];
    #pragma unroll
    for (int d = 0; d < 12; ++d) acc[d] += v * wrow[d];
  }
  #pragma unroll
  for (int d = 0; d < 12; ++d)
    VWt[(size_t)(h * DKH + q * 12 + d) * NB + b] = (__bf16)acc[d];
}

// ---------------- fused MFMA attention: ew-factored softmax ----------------
// grid = ns * 512 blocks x 256 threads. Wave = head h. m == 0 fixed reference.
// p_true = exp(qk*SCALE) * ew, ew = mask ? exp(w) : 0.
//   -> QK accumulator seeds ZERO (decoupled from weight convert; masked cols
//      give p = e*0 = 0 exactly); influence term = pt*ew (FMA, no extra exp);
//      Lw = sum(ew) accumulated per split (wstats pass deleted).
// Staging identical to proven R14: K+VW via global_load_lds (wave-private,
// zero barriers), source pre-swizzle, counted vmcnt(4) leaves W(t+1) in flight.
template<int MMODE>
__global__ __launch_bounds__(256, 4) void attn_kernel(
    const __bf16* __restrict__ Qb, const __bf16* __restrict__ Kb, const __bf16* __restrict__ VWt,
    const float* __restrict__ weight, const void* __restrict__ maskp,
    const int* __restrict__ maskflag,
    float* __restrict__ part, int tps)
{
  if (*maskflag != MMODE) return;   // wrong-mode instance: early out (grid-uniform)

  __shared__ __align__(16) __bf16 Kl[4 * 32 * 64];   // 16 KB, swizzled
  __shared__ __align__(16) __bf16 VWl[192 * 32];     // 12 KB, swizzled
  __shared__ __bf16 Ss[4][16][40];                   // 5 KB P staging

  const int t = threadIdx.x;
  const int lane = t & 63;
  const int h = t >> 6;
  const int c = lane & 15;          // actor col
  const int g = lane >> 4;
  const int g8 = g * 8;
  const int s = blockIdx.x >> 9;    // split
  const int a0 = (blockIdx.x & 511) * TA;
  const int tile0 = s * tps;
  const int tend = tile0 + tps;

  const unsigned char* m8 = (const unsigned char*)maskp;
  const float* mfp = (const float*)maskp;
  const int* m32 = (const int*)maskp;

  // Q fragment (B-operand): col a = c, k contiguous
  const __bf16* qp = Qb + ((size_t)(a0 + c) * NH + h) * 64 + g8;
  const bf16x8 qf0 = *(const bf16x8*)qp;
  const bf16x8 qf1 = *(const bf16x8*)(qp + 32);

  float lp = 0.f, Ap = 0.f, Lwp = 0.f;
  f32x4 o0 = {0.f,0.f,0.f,0.f}, o1 = {0.f,0.f,0.f,0.f}, o2 = {0.f,0.f,0.f,0.f};

  const size_t wrow = (size_t)(a0 + c) * NB + g * 4;

  // ---- lane-constant staging geometry (source pre-swizzle; dest linear) ----
  const int kswz = 8 * ((lane & 7) ^ ((lane >> 3) & 7));        // elements
  const int vswz = 8 * ((lane & 3) ^ ((lane >> 3) & 3));        // elements
  const size_t kgrow = (size_t)h * NB + (lane >> 3);            // + b0 per tile
  const size_t vgrow = (size_t)(h * 48 + (lane >> 2)) * NB;     // + b0 per tile
  __bf16* klw = Kl + h * 2048;      // wave's K region (4 KB)
  __bf16* vlw = VWl + h * 1536;     // wave's VW region (3 KB)

  // ---- read-side swizzled fragment offsets (lane-constant) ----
  const int swk  = 8 * (g ^ (c & 7));
  const int swk4 = 8 * ((g | 4) ^ (c & 7));
  const int swv  = 8 * (g ^ ((c >> 1) & 3));
  const __bf16* klr = Kl + h * 2048 + c * 64;
  const __bf16* vlr = VWl + (h * 48 + c) * 32 + swv;

  // ---- raw W prefetch slots (mode-specialized) ----
  float4 nw0, nw1;
  int nmx, nmy;          // mode 1
  int4 nmA, nmB;         // modes 0, 2
  {
    size_t gi = wrow + (size_t)tile0 * TB;
    nw0 = *(const float4*)(weight + gi);
    nw1 = *(const float4*)(weight + gi + 16);
    if constexpr (MMODE == 1)      { nmx = *(const int*)(m8 + gi); nmy = *(const int*)(m8 + gi + 16); }
    else if constexpr (MMODE == 2) { nmA = *(const int4*)(mfp + gi); nmB = *(const int4*)(mfp + gi + 16); }
    else                           { nmA = *(const int4*)(m32 + gi); nmB = *(const int4*)(m32 + gi + 16); }
  }

  for (int tile = tile0; tile < tend; ++tile) {
    const int b0 = tile * TB;

    // [1] stage K(t) 4 + VW(t) 3 -- async, no VGPR destinations
    {
      const __bf16* kg = Kb + (kgrow + b0) * 64 + kswz;
      GLDS(kg,            klw);
      GLDS(kg + 8 * 64,   klw + 512);
      GLDS(kg + 16 * 64,  klw + 1024);
      GLDS(kg + 24 * 64,  klw + 1536);
      const __bf16* vg = VWt + vgrow + b0 + vswz;
      GLDS(vg,            vlw);
      GLDS(vg + 16 * NB,  vlw + 512);
      GLDS(vg + 32 * NB,  vlw + 1024);
    }
    __builtin_amdgcn_sched_barrier(0);

    // [2] convert ew(t) = mask ? exp(w) : 0 (raws issued last body, retired)
    float ew[8];
    if constexpr (MMODE == 1) {
      unsigned ua = (unsigned)nmx, ub = (unsigned)nmy;
      ew[0] = (ua & 0xffu)         ? __expf(nw0.x) : 0.f;
      ew[1] = ((ua >> 8) & 0xffu)  ? __expf(nw0.y) : 0.f;
      ew[2] = ((ua >> 16) & 0xffu) ? __expf(nw0.z) : 0.f;
      ew[3] = (ua >> 24)           ? __expf(nw0.w) : 0.f;
      ew[4] = (ub & 0xffu)         ? __expf(nw1.x) : 0.f;
      ew[5] = ((ub >> 8) & 0xffu)  ? __expf(nw1.y) : 0.f;
      ew[6] = ((ub >> 16) & 0xffu) ? __expf(nw1.z) : 0.f;
      ew[7] = (ub >> 24)           ? __expf(nw1.w) : 0.f;
    } else if constexpr (MMODE == 2) {
      ew[0] = (((unsigned)nmA.x << 1) != 0u) ? __expf(nw0.x) : 0.f;
      ew[1] = (((unsigned)nmA.y << 1) != 0u) ? __expf(nw0.y) : 0.f;
      ew[2] = (((unsigned)nmA.z << 1) != 0u) ? __expf(nw0.z) : 0.f;
      ew[3] = (((unsigned)nmA.w << 1) != 0u) ? __expf(nw0.w) : 0.f;
      ew[4] = (((unsigned)nmB.x << 1) != 0u) ? __expf(nw1.x) : 0.f;
      ew[5] = (((unsigned)nmB.y << 1) != 0u) ? __expf(nw1.y) : 0.f;
      ew[6] = (((unsigned)nmB.z << 1) != 0u) ? __expf(nw1.z) : 0.f;
      ew[7] = (((unsigned)nmB.w << 1) != 0u) ? __expf(nw1.w) : 0.f;
    } else {
      ew[0] = nmA.x ? __expf(nw0.x) : 0.f;
      ew[1] = nmA.y ? __expf(nw0.y) : 0.f;
      ew[2] = nmA.z ? __expf(nw0.z) : 0.f;
      ew[3] = nmA.w ? __expf(nw0.w) : 0.f;
      ew[4] = nmB.x ? __expf(nw1.x) : 0.f;
      ew[5] = nmB.y ? __expf(nw1.y) : 0.f;
      ew[6] = nmB.z ? __expf(nw1.z) : 0.f;
      ew[7] = nmB.w ? __expf(nw1.w) : 0.f;
    }
    __builtin_amdgcn_sched_barrier(0);

    // [3] issue W(t+1) raws (behind stages in FIFO)
    {
      int tn = (tile + 1 < tend) ? tile + 1 : tile;
      size_t gi = wrow + (size_t)tn * TB;
      nw0 = *(const float4*)(weight + gi);
      nw1 = *(const float4*)(weight + gi + 16);
      if constexpr (MMODE == 1)      { nmx = *(const int*)(m8 + gi); nmy = *(const int*)(m8 + gi + 16); }
      else if constexpr (MMODE == 2) { nmA = *(const int4*)(mfp + gi); nmB = *(const int4*)(mfp + gi + 16); }
      else                           { nmA = *(const int4*)(m32 + gi); nmB = *(const int4*)(m32 + gi + 16); }
    }
    __builtin_amdgcn_sched_barrier(0);

    // [4] counted wait: drain the 7 stages, leave W(t+1)'s 4 loads in flight
    asm volatile("s_waitcnt vmcnt(4)" ::: "memory");
    __builtin_amdgcn_sched_barrier(0);

    // [5] QK (seed ZERO -- independent of ew) + softmax + PV
    bf16x8 kA0 = *(const bf16x8*)(klr + swk);
    bf16x8 kA1 = *(const bf16x8*)(klr + swk4);
    bf16x8 kB0 = *(const bf16x8*)(klr + 16 * 64 + swk);
    bf16x8 kB1 = *(const bf16x8*)(klr + 16 * 64 + swk4);
    bf16x8 vf0 = *(const bf16x8*)vlr;
    bf16x8 vf1 = *(const bf16x8*)(vlr + 16 * 32);
    bf16x8 vf2 = *(const bf16x8*)(vlr + 32 * 32);

    f32x4 acc0 = {0.f,0.f,0.f,0.f}, acc1 = {0.f,0.f,0.f,0.f};
    acc0 = MFMA16(kA0, qf0, acc0);
    acc0 = MFMA16(kA1, qf1, acc0);
    acc1 = MFMA16(kB0, qf0, acc1);
    acc1 = MFMA16(kB1, qf1, acc1);

    Lwp += (ew[0] + ew[1]) + (ew[2] + ew[3]) + (ew[4] + ew[5]) + (ew[6] + ew[7]);

    float pt[8];
    #pragma unroll
    for (int j = 0; j < 4; ++j) {
      float e0 = __expf(acc0[j] * SCALE);
      float e1 = __expf(acc1[j] * SCALE);
      float p0 = e0 * ew[j];
      float p1 = e1 * ew[4 + j];
      lp += p0 + p1;
      Ap += p0 * ew[j] + p1 * ew[4 + j];
      pt[j] = p0; pt[4 + j] = p1;
    }

    #pragma unroll
    for (int i = 0; i < 4; ++i) {
      Ss[h][c][g * 4 + i]      = (__bf16)pt[i];
      Ss[h][c][16 + g * 4 + i] = (__bf16)pt[4 + i];
    }
    __builtin_amdgcn_sched_barrier(0);
    bf16x8 pb = *(const bf16x8*)&Ss[h][c][g8];

    o0 = MFMA16(vf0, pb, o0);
    o1 = MFMA16(vf1, pb, o1);
    o2 = MFMA16(vf2, pb, o2);
  }

  // ---- one wave-reduce at the end; write partial record ----
  float l = rsumg(lp);
  float A = rsumg(Ap);
  float Lw = rsumg(Lwp);
  float* pr = part + ((size_t)s * NA + a0 + c) * PREC;
  #pragma unroll
  for (int j = 0; j < 4; ++j) {
    pr[h * 48 + g * 4 + j]      = o0[j];
    pr[h * 48 + 16 + g * 4 + j] = o1[j];
    pr[h * 48 + 32 + g * 4 + j] = o2[j];
  }
  if (g == 0) {
    pr[192 + h] = l;
    pr[196 + h] = A;
    if (h == 0) pr[200] = Lw;
  }
}

// ---------------- merge splits: plain sums (shared m == 0 reference) ----------------
__global__ __launch_bounds__(256) void merge_kernel(
    const float* __restrict__ part, const float* __restrict__ boe,
    float* __restrict__ out, int ns)
{
  __shared__ float fls[32][NH];      // 1/l per (a,h)
  __shared__ float infl[32][NH];
  __shared__ float lws[32];
  const int t = threadIdx.x;
  const int a0 = blockIdx.x * 32;

  if (t < 128) {
    int a = t >> 2, hh = t & 3;
    const float* rec = part + (size_t)(a0 + a) * PREC;
    float lst = 0.f, As = 0.f, Lws = 0.f;
    for (int s = 0; s < ns; ++s) {
      const float* r = rec + (size_t)s * NA * PREC;
      lst += r[192 + hh];
      As  += r[196 + hh];
      if (hh == 0) Lws += r[200];
    }
    float li = 1.f / lst;
    fls[a][hh] = li;
    infl[a][hh] = As * li;
    if (hh == 0) lws[a] = Lws;
  }
  __syncthreads();
  if (t < 32)
    out[(size_t)(a0 + t) * 49 + 48] =
        (infl[t][0] + infl[t][1] + infl[t][2] + infl[t][3]) / (4.f * lws[t]);
  for (int i = t; i < 32 * DKH; i += 256) {
    int a = i / DKH, dd = i - a * DKH;
    float acc = boe[dd];
    const float* rec = part + (size_t)(a0 + a) * PREC;
    for (int s = 0; s < ns; ++s) {
      const float* r = rec + (size_t)s * NA * PREC;
      #pragma unroll
      for (int hh = 0; hh < NH; ++hh)
        acc += fls[a][hh] * r[hh * 48 + dd];
    }
    out[(size_t)(a0 + a) * 49 + dd] = acc;
  }
}

extern "C" void kernel_launch(void* const* d_in, const int* in_sizes, int n_in,
                              void* d_out, int out_size, void* d_ws, size_t ws_size,
                              hipStream_t stream) {
  const float* a_z    = (const float*)d_in[0];
  const float* bv_z   = (const float*)d_in[1];
  const float* weight = (const float*)d_in[2];
  const void*  maskp  = d_in[3];
  const float* Wq = (const float*)d_in[4];
  const float* Wk = (const float*)d_in[5];
  const float* Wv = (const float*)d_in[6];
  const float* Wo = (const float*)d_in[7];
  const float* bq = (const float*)d_in[8];
  const float* bk = (const float*)d_in[9];
  const float* bvb = (const float*)d_in[10];
  const float* bo = (const float*)d_in[11];

  __bf16* Qb  = (__bf16*)d_ws;                      // [NA][4][64]
  __bf16* Kb  = Qb + (size_t)NA * 256;              // [4][NB][64]
  __bf16* Vtg = Kb + (size_t)4 * NB * 64;           // [192][NB]
  __bf16* VWt = Vtg + (size_t)DIM * NB;             // [192][NB]
  float* WoeT = (float*)(VWt + (size_t)DIM * NB);   // [192][48]
  float* boe  = WoeT + DIM * DKH;
  int*  mflag = (int*)(boe + 64);
  float* part = (float*)(mflag + 64);               // [ns][NA][204]

  size_t base = (size_t)((char*)(part) - (char*)d_ws);
  int ns = (ws_size >= base + (size_t)4 * NA * PREC * 4) ? 4 : 2;
  int tps = (NB / TB) / ns;

  prep_kernel<<<1573, 256, 0, stream>>>(a_z, bv_z, Wq, Wk, Wv, bq, bk, bvb, Wo, bo,
                                        maskp, Qb, Kb, Vtg, WoeT, boe, mflag);
  vw_kernel<<<NB / 16, 256, 0, stream>>>(Vtg, WoeT, VWt);
  attn_kernel<1><<<ns * 512, 256, 0, stream>>>(Qb, Kb, VWt, weight, maskp, mflag, part, tps);
  attn_kernel<0><<<ns * 512, 256, 0, stream>>>(Qb, Kb, VWt, weight, maskp, mflag, part, tps);
  attn_kernel<2><<<ns * 512, 256, 0, stream>>>(Qb, Kb, VWt, weight, maskp, mflag, part, tps);
  merge_kernel<<<NA / 32, 256, 0, stream>>>(part, boe, (float*)d_out, ns);
}